// Round 1
// baseline (751.059 us; speedup 1.0000x reference)
//
#include <hip/hip_runtime.h>
#include <math.h>

#define B_  64
#define H_  224
#define W_  224
#define C_  32
#define HW_ (H_ * W_)

// ---------------------------------------------------------------------------
// Kernel 1: partial spatial sums per (sample, channel).
// Grid: B_ * 98 blocks, 256 threads. Each block handles 512 pixels.
// Thread t: channel-quad c4 = t&7, pixel-row prow = t>>3 (8 pixels/wave,
// 1 KB contiguous per wave iteration, float4 loads).
// ---------------------------------------------------------------------------
__global__ __launch_bounds__(256) void sum_kernel(const float* __restrict__ x,
                                                  float* __restrict__ sums) {
    const int blk   = blockIdx.x;
    const int b     = blk / 98;
    const int chunk = blk % 98;
    const int t     = threadIdx.x;
    const int c4    = t & 7;
    const int prow  = t >> 3;

    const float4* xb = (const float4*)(x + (size_t)b * HW_ * C_);
    const int pos0 = chunk * 512 + prow;

    float4 acc = make_float4(0.f, 0.f, 0.f, 0.f);
#pragma unroll
    for (int it = 0; it < 16; ++it) {
        const int pos = pos0 + it * 32;
        const float4 v = xb[(size_t)pos * 8 + c4];
        acc.x += v.x; acc.y += v.y; acc.z += v.z; acc.w += v.w;
    }

    __shared__ float4 s[256];
    s[t] = acc;
    __syncthreads();
#pragma unroll
    for (int stride = 128; stride >= 8; stride >>= 1) {
        if (t < stride) {
            const float4 o = s[t + stride];
            s[t].x += o.x; s[t].y += o.y; s[t].z += o.z; s[t].w += o.w;
        }
        __syncthreads();
    }
    if (t < 8) {
        const float4 v = s[t];
        atomicAdd(&sums[b * C_ + t * 4 + 0], v.x);
        atomicAdd(&sums[b * C_ + t * 4 + 1], v.y);
        atomicAdd(&sums[b * C_ + t * 4 + 2], v.z);
        atomicAdd(&sums[b * C_ + t * 4 + 3], v.w);
    }
}

// ---------------------------------------------------------------------------
// Kernel 2: logits + argmax per sample. One block, 64 threads.
// jnp.argmax tie-break = first max -> strict > comparison.
// ---------------------------------------------------------------------------
__global__ void classify_kernel(const float* __restrict__ sums,
                                const float* __restrict__ Wc,   // [C_,4] row-major
                                const float* __restrict__ bc,   // [4]
                                int* __restrict__ kk) {
    const int b = threadIdx.x;
    if (b >= B_) return;
    float m[C_];
    const float inv = 1.0f / (float)HW_;
#pragma unroll
    for (int c = 0; c < C_; ++c) m[c] = sums[b * C_ + c] * inv;

    float best = -INFINITY;
    int bi = 0;
#pragma unroll
    for (int j = 0; j < 4; ++j) {
        float l = bc[j];
#pragma unroll
        for (int c = 0; c < C_; ++c) l += m[c] * Wc[c * 4 + j];
        if (l > best) { best = l; bi = j; }
    }
    kk[b] = bi;
}

// ---------------------------------------------------------------------------
// Kernel 3: per-sample rot90^k gather. One block per (b, output row i).
// Writes: perfectly coalesced float4. Reads: 128 B contiguous per pixel
// (full cache-line utilization even when row-strided for k=1/3).
//   k=0: src=(i,j)  k=1: src=(j,W-1-i)  k=2: src=(H-1-i,W-1-j)  k=3: src=(H-1-j,i)
// ---------------------------------------------------------------------------
__global__ __launch_bounds__(256) void rotate_kernel(const float* __restrict__ x,
                                                     const int* __restrict__ kk,
                                                     float* __restrict__ out) {
    const int blk = blockIdx.x;       // b*H_ + i
    const int b = blk / H_;
    const int i = blk % H_;
    const int k = kk[b];

    const float4* xb = (const float4*)(x + (size_t)b * HW_ * C_);
    float4* ob = (float4*)(out + ((size_t)b * HW_ + (size_t)i * W_) * C_);

    const int t = threadIdx.x;
#pragma unroll
    for (int rep = 0; rep < 7; ++rep) {           // W_*8 / 256 = 7 exactly
        const int idx = rep * 256 + t;
        const int j  = idx >> 3;
        const int c4 = idx & 7;
        int si, sj;
        switch (k) {
            case 0:  si = i;          sj = j;          break;
            case 1:  si = j;          sj = W_ - 1 - i; break;
            case 2:  si = H_ - 1 - i; sj = W_ - 1 - j; break;
            default: si = H_ - 1 - j; sj = i;          break;
        }
        ob[idx] = xb[((size_t)si * W_ + sj) * 8 + c4];
    }
}

// ---------------------------------------------------------------------------
extern "C" void kernel_launch(void* const* d_in, const int* in_sizes, int n_in,
                              void* d_out, int out_size, void* d_ws, size_t ws_size,
                              hipStream_t stream) {
    const float* x   = (const float*)d_in[0];
    const float* Wc  = (const float*)d_in[1];
    const float* bc  = (const float*)d_in[2];
    float* out       = (float*)d_out;

    float* sums = (float*)d_ws;                       // B_*C_ floats = 8192 B
    int*   kk   = (int*)((char*)d_ws + B_ * C_ * 4);  // B_ ints

    // ws is poisoned 0xAA before every launch -> zero the accumulators.
    hipMemsetAsync(sums, 0, B_ * C_ * sizeof(float), stream);

    sum_kernel<<<B_ * 98, 256, 0, stream>>>(x, sums);
    classify_kernel<<<1, 64, 0, stream>>>(sums, Wc, bc, kk);
    rotate_kernel<<<B_ * H_, 256, 0, stream>>>(x, kk, out);
}

// Round 2
// 744.890 us; speedup vs baseline: 1.0083x; 1.0083x over previous
//
#include <hip/hip_runtime.h>
#include <math.h>

#define B_  64
#define H_  224
#define W_  224
#define C_  32
#define HW_ (H_ * W_)
#define T_  16            // pixel tile edge
#define TILES_ (W_ / T_)  // 14

// ---------------------------------------------------------------------------
// Kernel 1: partial spatial sums per (sample, channel).
// Grid: B_ * 98 blocks, 256 threads. Each block reduces 512 consecutive
// pixels (64 KB contiguous) with float4 loads; LDS tree; 8 atomicAdds.
// ---------------------------------------------------------------------------
__global__ __launch_bounds__(256) void sum_kernel(const float* __restrict__ x,
                                                  float* __restrict__ sums) {
    const int blk   = blockIdx.x;
    const int b     = blk / 98;
    const int chunk = blk % 98;
    const int t     = threadIdx.x;
    const int c4    = t & 7;
    const int prow  = t >> 3;

    const float4* xb = (const float4*)(x + (size_t)b * HW_ * C_);
    const int pos0 = chunk * 512 + prow;

    float4 acc = make_float4(0.f, 0.f, 0.f, 0.f);
#pragma unroll
    for (int it = 0; it < 16; ++it) {
        const int pos = pos0 + it * 32;
        const float4 v = xb[(size_t)pos * 8 + c4];
        acc.x += v.x; acc.y += v.y; acc.z += v.z; acc.w += v.w;
    }

    __shared__ float4 s[256];
    s[t] = acc;
    __syncthreads();
#pragma unroll
    for (int stride = 128; stride >= 8; stride >>= 1) {
        if (t < stride) {
            const float4 o = s[t + stride];
            s[t].x += o.x; s[t].y += o.y; s[t].z += o.z; s[t].w += o.w;
        }
        __syncthreads();
    }
    if (t < 8) {
        const float4 v = s[t];
        atomicAdd(&sums[b * C_ + t * 4 + 0], v.x);
        atomicAdd(&sums[b * C_ + t * 4 + 1], v.y);
        atomicAdd(&sums[b * C_ + t * 4 + 2], v.z);
        atomicAdd(&sums[b * C_ + t * 4 + 3], v.w);
    }
}

// ---------------------------------------------------------------------------
// Kernel 2: logits + argmax per sample. One block, 64 threads.
// jnp.argmax tie-break = first max -> strict > comparison.
// ---------------------------------------------------------------------------
__global__ void classify_kernel(const float* __restrict__ sums,
                                const float* __restrict__ Wc,   // [C_,4]
                                const float* __restrict__ bc,   // [4]
                                int* __restrict__ kk) {
    const int b = threadIdx.x;
    if (b >= B_) return;
    float m[C_];
    const float inv = 1.0f / (float)HW_;
#pragma unroll
    for (int c = 0; c < C_; ++c) m[c] = sums[b * C_ + c] * inv;

    float best = -INFINITY;
    int bi = 0;
#pragma unroll
    for (int j = 0; j < 4; ++j) {
        float l = bc[j];
#pragma unroll
        for (int c = 0; c < C_; ++c) l += m[c] * Wc[c * 4 + j];
        if (l > best) { best = l; bi = j; }
    }
    kk[b] = bi;
}

// ---------------------------------------------------------------------------
// Kernel 3: tiled rot90^k. One block per (b, 16x16 output pixel tile).
// For every k the source of an output tile is a CONTIGUOUS 16x16 source
// tile; we load it row-major (16 x 2 KB segments), resolve the in-tile
// reflection/transpose via LDS, and write output row-major coalesced.
//   out[i][j] = x[si][sj]:
//   k=0: (i,j)   k=1: (j, W-1-i)   k=2: (H-1-i, W-1-j)   k=3: (H-1-j, i)
// LDS = 16*16 pixels * 128 B = 32 KB -> 5 blocks/CU. Each 8-lane phase of a
// b128 wave read touches one pixel's 128 contiguous bytes = all 32 banks,
// so the transposed read pattern is bank-conflict-free.
// Samples iterated in REVERSE so the rotate pass first reads the tail of x,
// which sum_kernel streamed most recently (partial L3 reuse; x=411MB>256MB L3).
// ---------------------------------------------------------------------------
__global__ __launch_bounds__(256) void rotate_kernel(const float* __restrict__ x,
                                                     const int* __restrict__ kk,
                                                     float* __restrict__ out) {
    const int blk  = blockIdx.x;
    const int b    = (B_ - 1) - blk / (TILES_ * TILES_);
    const int trem = blk % (TILES_ * TILES_);
    const int ti   = trem / TILES_;
    const int tj   = trem % TILES_;
    const int i0   = ti * T_;
    const int j0   = tj * T_;
    const int k    = kk[b];

    int sr0, sc0;
    switch (k) {
        case 0:  sr0 = i0;           sc0 = j0;           break;
        case 1:  sr0 = j0;           sc0 = W_ - T_ - i0; break;
        case 2:  sr0 = H_ - T_ - i0; sc0 = W_ - T_ - j0; break;
        default: sr0 = H_ - T_ - j0; sc0 = i0;           break;
    }

    __shared__ float4 tile[T_ * T_ * 8];   // 32 KB

    const float4* xb = (const float4*)(x + (size_t)b * HW_ * C_);
    float4*       ob = (float4*)(out + (size_t)b * HW_ * C_);

    const int t = threadIdx.x;

    // Load: 2048 float4s (8/thread). Consecutive lidx -> consecutive source
    // bytes within a row: 16 segments of 2 KB.
#pragma unroll
    for (int rep = 0; rep < 8; ++rep) {
        const int lidx = rep * 256 + t;
        const int r  = lidx >> 7;          // pixel row in tile
        const int c  = (lidx >> 3) & 15;   // pixel col in tile
        const int c4 = lidx & 7;
        tile[lidx] = xb[((size_t)(sr0 + r) * W_ + (sc0 + c)) * 8 + c4];
    }
    __syncthreads();

    // Store: output row-major coalesced; LDS gather per-k.
#pragma unroll
    for (int rep = 0; rep < 8; ++rep) {
        const int oidx = rep * 256 + t;
        const int di = oidx >> 7;
        const int dj = (oidx >> 3) & 15;
        const int c4 = oidx & 7;
        int r, c;
        switch (k) {
            case 0:  r = di;        c = dj;        break;
            case 1:  r = dj;        c = 15 - di;   break;
            case 2:  r = 15 - di;   c = 15 - dj;   break;
            default: r = 15 - dj;   c = di;        break;
        }
        ob[((size_t)(i0 + di) * W_ + (j0 + dj)) * 8 + c4] = tile[(r * 16 + c) * 8 + c4];
    }
}

// ---------------------------------------------------------------------------
extern "C" void kernel_launch(void* const* d_in, const int* in_sizes, int n_in,
                              void* d_out, int out_size, void* d_ws, size_t ws_size,
                              hipStream_t stream) {
    const float* x   = (const float*)d_in[0];
    const float* Wc  = (const float*)d_in[1];
    const float* bc  = (const float*)d_in[2];
    float* out       = (float*)d_out;

    float* sums = (float*)d_ws;                       // B_*C_ floats
    int*   kk   = (int*)((char*)d_ws + B_ * C_ * 4);  // B_ ints

    hipMemsetAsync(sums, 0, B_ * C_ * sizeof(float), stream);

    sum_kernel<<<B_ * 98, 256, 0, stream>>>(x, sums);
    classify_kernel<<<1, 64, 0, stream>>>(sums, Wc, bc, kk);
    rotate_kernel<<<B_ * TILES_ * TILES_, 256, 0, stream>>>(x, kk, out);
}